// Round 4
// baseline (293.528 us; speedup 1.0000x reference)
//
#include <hip/hip_runtime.h>
#include <hip/hip_bf16.h>

#define B_ 32
#define S_ 2048
#define D_ 512
#define M_ (B_*S_)   // 65536 rows

typedef __bf16 bf16x8 __attribute__((ext_vector_type(8)));
typedef float  f32x4  __attribute__((ext_vector_type(4)));

__device__ __forceinline__ float tanh_fast(float x){
  float e2 = __expf(2.f * x);                    // inf for large x -> rcp=0 -> 1
  return 1.f - 2.f * __builtin_amdgcn_rcpf(e2 + 1.f);
}

__device__ __forceinline__ bf16x8 pack8(f32x4 r0, f32x4 r1){
  bf16x8 t;
  t[0]=(__bf16)r0[0]; t[1]=(__bf16)r0[1]; t[2]=(__bf16)r0[2]; t[3]=(__bf16)r0[3];
  t[4]=(__bf16)r1[0]; t[5]=(__bf16)r1[1]; t[6]=(__bf16)r1[2]; t[7]=(__bf16)r1[3];
  return t;
}

// async 16B/lane global->LDS DMA (wave-uniform LDS base + lane*16)
__device__ __forceinline__ void gl_lds16(const float* g, float* l){
  __builtin_amdgcn_global_load_lds(
      (const __attribute__((address_space(1))) void*)g,
      (__attribute__((address_space(3))) void*)l, 16, 0, 0);
}

// ---- prep: (a) reorder w_v into bf16 MFMA B-frag order, (b) qproj ----
// blocks 0..127: reorder. frag f = ks*32 + nt; lane holds
//   B[k = ks*32 + quad*8 + j][n = nt*16 + lm], j=0..7.
// blocks 128..255: qp[b,d] = query[b,:] @ w_q[:,d] + bias[d]
__global__ void k_prep(const float* __restrict__ wv,
                       unsigned short* __restrict__ wvr,
                       const float* __restrict__ q,
                       const float* __restrict__ wq,
                       const float* __restrict__ bias,
                       float* __restrict__ qp){
  __shared__ float qs[D_];
  __shared__ float red2[2][128];
  int bid = blockIdx.x, t = threadIdx.x;
  if (bid < 128){
    int frag = bid*4 + (t>>6);      // 0..511
    int lane = t & 63;
    int ks = frag >> 5, nt = frag & 31;
    int k0 = ks*32 + (lane>>4)*8;
    int d  = nt*16 + (lane&15);
    bf16x8 v;
    #pragma unroll
    for (int j=0;j<8;++j) v[j] = (__bf16)wv[(k0+j)*D_ + d];
    *reinterpret_cast<uint4*>(wvr + ((size_t)frag*64 + lane)*8) =
        __builtin_bit_cast(uint4, v);
  } else {
    int idx = bid - 128;            // 0..127
    int b = idx >> 2, ch = idx & 3;
    int dl = t & 127, eg = t >> 7;  // 2-way K split
    int d  = ch*128 + dl;
    for (int e=t; e<D_; e+=256) qs[e] = q[b*D_+e];
    __syncthreads();
    float a = 0.f;
    #pragma unroll 8
    for (int i=0;i<256;++i){
      int e = eg*256 + i;
      a = fmaf(qs[e], wq[(size_t)e*D_+d], a);
    }
    red2[eg][dl] = a;
    __syncthreads();
    if (eg == 0) qp[b*D_+d] = red2[0][dl] + red2[1][dl] + bias[d];
  }
}

// ---- fused (value@w_v + qproj + loc) -> tanh -> dot(score_w) -> scores ----
// v5: 32-row blocks, FULL rows staged once via 64x gl_lds16 (1KB contiguous
// each, 64KB in flight per block), ONE barrier, then all 16 K-chunks from
// LDS with zero mid-loop syncs. Kills the per-period vmcnt(0) drain that
// made v2/v3/v4 all land at ~80us. DMA and B-frag loads no longer share
// the vmcnt FIFO across a wait. Wave = 2 M-tiles x 8 N-tiles (acc[2][8]).
// LDS [32][512] f32, 16B granules XOR-swizzled within each row:
//   phys_g = g ^ x(row), x(row) = ((row&7)<<1)|((row>>3)&1)
// (linear DMA dest; inverse-swizzled global source; swizzled ds_read.)
__launch_bounds__(256, 2)
__global__ void k_energy(const float* __restrict__ value,
                         const unsigned short* __restrict__ wvr,
                         const float* __restrict__ qp,
                         const float* __restrict__ energy,
                         const float* __restrict__ conv_w,
                         const float* __restrict__ conv_b,
                         const float* __restrict__ score_w,
                         float* __restrict__ scores){
  const int t    = threadIdx.x;
  const int wave = t >> 6;
  const int lane = t & 63;
  const int quad = lane >> 4;
  const int lm   = lane & 15;
  const int row0 = blockIdx.x * 32;
  const int b    = row0 >> 11;          // S=2048
  const int s0   = row0 & (S_-1);

  __shared__ __align__(16) float Af[32*512];   // 64 KB

  // ---- stage: instr j (j = wave*16+i) covers row j>>1, 1KB half (j&1) ----
  // LDS granule G = j*64+lane (linear). logical g = (G&127) ^ x(row).
  #pragma unroll
  for (int i=0;i<16;++i){
    int j  = wave*16 + i;
    int r  = j >> 1;
    int x  = ((r&7)<<1) | ((r>>3)&1);
    int pg = ((j&1)<<6) | lane;
    gl_lds16(value + (size_t)(row0+r)*D_ + ((pg ^ x)<<2), &Af[j*256]);
  }

  f32x4 acc[2][8];
  #pragma unroll
  for (int mt=0;mt<2;++mt)
    #pragma unroll
    for (int n=0;n<8;++n)
      acc[mt][n] = (f32x4){0.f,0.f,0.f,0.f};

  // wave's 8 N-tiles: ntl = wave*8 + n ; frag (c, ntl) at (c*32+ntl)*512 shorts
  const unsigned short* bP = wvr + ((size_t)(wave*8)*64 + lane)*8;
  bf16x8 bc[8];
  #pragma unroll
  for (int n=0;n<8;++n)
    bc[n] = __builtin_bit_cast(bf16x8,
        *reinterpret_cast<const uint4*>(bP + (size_t)n*512));

  __syncthreads();   // single drain: all 64KB staged, B(0) in regs

  const int fl = ((lm&7)<<1) | (lm>>3);
  for (int c=0;c<16;++c){
    bf16x8 a[2];
    #pragma unroll
    for (int mt=0;mt<2;++mt){
      const float* base = &Af[(mt*16+lm)*512];
      int ga = (c*8 + quad*2) ^ fl;
      f32x4 r0 = *reinterpret_cast<const f32x4*>(base + ga*4);        // k 0..3
      f32x4 r1 = *reinterpret_cast<const f32x4*>(base + (ga^1)*4);    // k 4..7
      a[mt] = pack8(r0, r1);
    }
    __builtin_amdgcn_s_setprio(1);
    #pragma unroll
    for (int n=0;n<8;++n){
      bf16x8 bv = bc[n];
      if (c < 15)   // rolling refill for chunk c+1 right after last use
        bc[n] = __builtin_bit_cast(bf16x8,
            *reinterpret_cast<const uint4*>(bP + (size_t)((c+1)*32+n)*512));
      acc[0][n] = __builtin_amdgcn_mfma_f32_16x16x32_bf16(a[0], bv, acc[0][n], 0,0,0);
      acc[1][n] = __builtin_amdgcn_mfma_f32_16x16x32_bf16(a[1], bv, acc[1][n], 0,0,0);
    }
    __builtin_amdgcn_s_setprio(0);
  }

  // ---- epilogue: per-lane d set = wave*128 + n*16 + lm ----
  float sw[8], c0[8], c1[8], c2[8], cb[8], qv[8];
  #pragma unroll
  for (int n=0; n<8; ++n){
    int d = wave*128 + n*16 + lm;
    sw[n] = score_w[d];
    c0[n] = conv_w[d*3+0];
    c1[n] = conv_w[d*3+1];
    c2[n] = conv_w[d*3+2];
    cb[n] = conv_b[d];
    qv[n] = qp[b*D_+d];
  }
  __syncthreads();           // all waves done reading Af -> reuse as reduce buf
  float* red = &Af[0];       // 4 waves x 32 rows
  const float* eB = energy + b*S_;
  #pragma unroll
  for (int mt=0; mt<2; ++mt){
    #pragma unroll
    for (int r=0;r<4;++r){
      int sl = mt*16 + quad*4 + r;              // C/D layout: row=quad*4+reg
      int s  = s0 + sl;
      float em1 = (s > 0)    ? eB[s-1] : 0.f;
      float e0  =              eB[s];
      float ep1 = (s < S_-1) ? eB[s+1] : 0.f;
      float p = 0.f;
      #pragma unroll
      for (int n=0; n<8; ++n){
        float h = acc[mt][n][r] + qv[n]
                + fmaf(c0[n],em1, fmaf(c1[n],e0, fmaf(c2[n],ep1, cb[n])));
        p = fmaf(sw[n], tanh_fast(h), p);
      }
      #pragma unroll
      for (int m=1; m<16; m<<=1) p += __shfl_xor(p, m, 64);   // reduce 16 cols
      if (lm == 0) red[wave*32 + sl] = p;
    }
  }
  __syncthreads();
  if (t < 32)
    scores[row0 + t] = red[t] + red[32+t] + red[64+t] + red[96+t];
}

// ---- softmax over S per batch; also zeroes out_ctx for the atomic ctx ----
__global__ void k_softmax(const float* __restrict__ sp,
                          const float* __restrict__ score_b,
                          float* __restrict__ out_align,
                          float* __restrict__ out_ctx){
  int b = blockIdx.x, t = threadIdx.x;
  int lane = t & 63, wid = t >> 6;
  out_ctx[b*D_ + t]       = 0.f;    // zero context accumulators (512/block)
  out_ctx[b*D_ + 256 + t] = 0.f;
  float sb = score_b[0];
  float v[8], mx = -3.4e38f;
  #pragma unroll
  for (int i=0;i<8;++i){
    float sc = sp[b*S_ + t + i*256] + sb;
    v[i] = sc;
    mx = fmaxf(mx, sc);
  }
  __shared__ float red[4], red2[4];
  #pragma unroll
  for (int m=1;m<64;m<<=1) mx = fmaxf(mx, __shfl_xor(mx, m, 64));
  if (lane==0) red[wid] = mx;
  __syncthreads();
  mx = fmaxf(fmaxf(red[0],red[1]), fmaxf(red[2],red[3]));
  float sum = 0.f;
  #pragma unroll
  for (int i=0;i<8;++i){ v[i] = __expf(v[i]-mx); sum += v[i]; }
  #pragma unroll
  for (int m=1;m<64;m<<=1) sum += __shfl_xor(sum, m, 64);
  if (lane==0) red2[wid] = sum;
  __syncthreads();
  sum = red2[0]+red2[1]+red2[2]+red2[3];
  float inv = 1.f/sum;
  #pragma unroll
  for (int i=0;i<8;++i) out_align[b*S_ + t + i*256] = v[i]*inv;
}

// ---- context: block (sc,b) covers 64 s rows; atomicAdd into out_ctx ----
__global__ void k_ctx_part(const float* __restrict__ value,
                           const float* __restrict__ align,
                           float* __restrict__ out_ctx){
  int b = blockIdx.y, sc = blockIdx.x;    // sc 0..31
  int t = threadIdx.x;
  int r = t >> 7;            // 0..1 (s subgroup)
  int c = (t & 127) * 4;     // d base, 4 floats = 16B per thread
  __shared__ float al[64];
  if (t < 64) al[t] = align[b*S_ + sc*64 + t];
  __syncthreads();
  f32x4 acc = (f32x4){0.f,0.f,0.f,0.f};
  const float* vbase = value + ((size_t)(b*S_ + sc*64 + r))*D_ + c;
  #pragma unroll 8
  for (int i=0;i<32;++i){
    f32x4 v = *reinterpret_cast<const f32x4*>(vbase + (size_t)(2*i)*D_);
    acc += al[2*i+r] * v;
  }
  __shared__ float lred[2][D_];
  #pragma unroll
  for (int j=0;j<4;++j) lred[r][c+j] = acc[j];
  __syncthreads();
  if (r == 0){
    #pragma unroll
    for (int j=0;j<4;++j)
      atomicAdd(&out_ctx[(size_t)b*D_ + c + j], lred[0][c+j] + lred[1][c+j]);
  }
}

extern "C" void kernel_launch(void* const* d_in, const int* in_sizes, int n_in,
                              void* d_out, int out_size, void* d_ws, size_t ws_size,
                              hipStream_t stream){
  const float* query   = (const float*)d_in[0];
  const float* value   = (const float*)d_in[1];
  const float* energy  = (const float*)d_in[2];
  const float* conv_w  = (const float*)d_in[3];
  const float* conv_b  = (const float*)d_in[4];
  const float* w_q     = (const float*)d_in[5];
  const float* w_v     = (const float*)d_in[6];
  const float* bias    = (const float*)d_in[7];
  const float* score_w = (const float*)d_in[8];
  const float* score_b = (const float*)d_in[9];

  char* ws = (char*)d_ws;
  unsigned short* wvr = (unsigned short*)(ws);            // 512 KB (bf16 frags)
  float* qp    = (float*)(ws + (512<<10));                // 64 KB
  float* sp    = (float*)(ws + (576<<10));                // 256 KB (65536 f32)
  // total ~832 KB

  float* out_ctx   = (float*)d_out;                       // [B, D] fp32
  float* out_align = out_ctx + B_*D_;                     // [B, S] fp32

  k_prep    <<<dim3(256),     dim3(256), 0, stream>>>(w_v, wvr, query, w_q, bias, qp);
  k_energy  <<<dim3(M_/32),   dim3(256), 0, stream>>>(value, wvr, qp, energy,
                                                      conv_w, conv_b, score_w, sp);
  k_softmax <<<dim3(B_),      dim3(256), 0, stream>>>(sp, score_b, out_align, out_ctx);
  k_ctx_part<<<dim3(32,B_),   dim3(256), 0, stream>>>(value, out_align, out_ctx);
}